// Round 3
// baseline (1676.995 us; speedup 1.0000x reference)
//
#include <hip/hip_runtime.h>

typedef unsigned short u16;
typedef unsigned int   u32;

#define BB   64
#define TT   256
#define DIN  5881
#define DM   64
#define DI   128
#define NST  16
#define DTR  4
#define TCH  32      // timestep chunk
#define NCH  8       // chunks per batch

__device__ __forceinline__ float bf2f(u16 u) {
    union { u32 i; float f; } v; v.i = ((u32)u) << 16; return v.f;
}
__device__ __forceinline__ u16 f2bf(float f) {
    union { float f; u32 i; } v; v.f = f;
    u32 x = v.i;
    return (u16)((x + 0x7FFFu + ((x >> 16) & 1u)) >> 16);
}

typedef __attribute__((ext_vector_type(8))) short short8;
typedef __attribute__((ext_vector_type(4))) float floatx4;

// dtype-aware element loads
template<bool BF16>
__device__ __forceinline__ float ld1(const void* p, size_t i) {
    if (BF16) return bf2f(((const u16*)p)[i]);
    else      return ((const float*)p)[i];
}
template<bool BF16>
__device__ __forceinline__ u16 ldb(const void* p, size_t i) {   // load as bf16 bits
    if (BF16) return ((const u16*)p)[i];
    else      return f2bf(((const float*)p)[i]);
}
template<bool BF16>
__device__ __forceinline__ void st1(void* p, size_t i, float v) {
    if (BF16) ((u16*)p)[i] = f2bf(v);
    else      ((float*)p)[i] = v;
}

template<bool BF16>
__device__ __forceinline__ void body(
        const void* inp,   const void* Wenc, const void* benc, const void* W_in,
        const void* conv_w,const void* conv_b,const void* W_x, const void* W_dt,
        const void* b_dt,  const void* A_log,const void* D_skip,const void* W_out,
        const void* W_fc,  const void* b_fc, const void* W_mu, const void* b_mu,
        const void* W_sig, const void* b_sig, void* out,
        u16* As, u16* Bs, u16* zc, u16* xl, u16* gl, u16* xcb,
        float* xd2, u16* dtl, float* yb, float* es, float* xs) {

    const int b    = blockIdx.x;
    const int tid  = threadIdx.x;
    const int wave = tid >> 6, lane = tid & 63;
    const int quad = lane >> 4, r16 = lane & 15;
    const int dd   = tid & 127;

    // ---- per-thread parameter preloads ----
    float cw[4], cb, wdt[4], bdt;
    #pragma unroll
    for (int k = 0; k < 4; ++k) cw[k] = ld1<BF16>(conv_w, dd * 4 + k);
    cb = ld1<BF16>(conv_b, dd);
    #pragma unroll
    for (int r = 0; r < 4; ++r) wdt[r] = ld1<BF16>(W_dt, dd * 4 + r);
    bdt = ld1<BF16>(b_dt, dd);

    float Areg[NST], hreg[NST], Dv = 0.f, accy = 0.f;
    #pragma unroll
    for (int n = 0; n < NST; ++n) hreg[n] = 0.f;
    if (tid < DI) {
        #pragma unroll
        for (int n = 0; n < NST; ++n) Areg[n] = -expf(ld1<BF16>(A_log, tid * NST + n));
        Dv = ld1<BF16>(D_skip, tid);
    } else {
        #pragma unroll
        for (int n = 0; n < NST; ++n) Areg[n] = 0.f;
    }

    // xz B-frags: W_in rows (wave*64 + nt*16 + r16), K=64 (2 k-tiles)
    short8 win[4][2];
    #pragma unroll
    for (int nt = 0; nt < 4; ++nt)
        #pragma unroll
        for (int kt = 0; kt < 2; ++kt) {
            size_t base = (size_t)(wave * 64 + nt * 16 + r16) * DM + kt * 32 + quad * 8;
            short8 v;
            #pragma unroll
            for (int e = 0; e < 8; ++e) v[e] = (short)ldb<BF16>(W_in, base + e);
            win[nt][kt] = v;
        }

    // xdbl B-frags: W_x rows j = wave*16 + r16 (waves 0..2), K=128 (4 k-tiles)
    short8 wx[4];
    {
        int j = wave * 16 + r16;
        #pragma unroll
        for (int kt = 0; kt < 4; ++kt) {
            short8 v = (short8){0,0,0,0,0,0,0,0};
            if (wave < 3 && j < DTR + 2 * NST) {
                size_t base = (size_t)j * DI + kt * 32 + quad * 8;
                #pragma unroll
                for (int e = 0; e < 8; ++e) v[e] = (short)ldb<BF16>(W_x, base + e);
            }
            wx[kt] = v;
        }
    }

    // zero conv halo rows 0..2
    for (int i = tid; i < 3 * 128; i += 256) xl[i] = 0;
    __syncthreads();

    const int rowbase = b * TT;
    const int asr = tid >> 3, ask = (tid & 7) * 8;   // A: 32 rows x 64 k
    const int bsr = tid >> 2, bsk = (tid & 3) * 16;  // B: 64 rows x 64 k
    const int emt = wave & 1, entb = (wave >> 1) * 2;

    for (int c = 0; c < NCH; ++c) {
        // ===== 1) encoder GEMM: z rows [c*32, c*32+32) =====
        floatx4 ze0 = (floatx4){0,0,0,0}, ze1 = (floatx4){0,0,0,0};
        const size_t aoff = (size_t)(rowbase + c * TCH + asr) * DIN;
        const size_t boff = (size_t)bsr * DIN;
        const int NK = (DIN + 63) / 64;  // 92
        for (int it = 0; it < NK; ++it) {
            int ka = it * 64 + ask;
            int kb = it * 64 + bsk;
            u32 pa[4], pb[8];
            if (it < NK - 1) {
                #pragma unroll
                for (int j = 0; j < 4; ++j) {
                    u32 a0 = ldb<BF16>(inp, aoff + ka + 2 * j);
                    u32 a1 = ldb<BF16>(inp, aoff + ka + 2 * j + 1);
                    pa[j] = a0 | (a1 << 16);
                }
                #pragma unroll
                for (int j = 0; j < 8; ++j) {
                    u32 b0 = ldb<BF16>(Wenc, boff + kb + 2 * j);
                    u32 b1 = ldb<BF16>(Wenc, boff + kb + 2 * j + 1);
                    pb[j] = b0 | (b1 << 16);
                }
            } else {
                #pragma unroll
                for (int j = 0; j < 4; ++j) {
                    int k0 = ka + 2 * j, k1 = k0 + 1;
                    u32 a0 = (k0 < DIN) ? (u32)ldb<BF16>(inp, aoff + k0) : 0u;
                    u32 a1 = (k1 < DIN) ? (u32)ldb<BF16>(inp, aoff + k1) : 0u;
                    pa[j] = a0 | (a1 << 16);
                }
                #pragma unroll
                for (int j = 0; j < 8; ++j) {
                    int k0 = kb + 2 * j, k1 = k0 + 1;
                    u32 b0 = (k0 < DIN) ? (u32)ldb<BF16>(Wenc, boff + k0) : 0u;
                    u32 b1 = (k1 < DIN) ? (u32)ldb<BF16>(Wenc, boff + k1) : 0u;
                    pb[j] = b0 | (b1 << 16);
                }
            }
            *(uint4*)(&As[asr * 72 + ask]) = make_uint4(pa[0], pa[1], pa[2], pa[3]);
            *(uint4*)(&Bs[bsr * 72 + bsk])     = make_uint4(pb[0], pb[1], pb[2], pb[3]);
            *(uint4*)(&Bs[bsr * 72 + bsk + 8]) = make_uint4(pb[4], pb[5], pb[6], pb[7]);
            __syncthreads();
            #pragma unroll
            for (int kk = 0; kk < 2; ++kk) {
                short8 af  = *(const short8*)(&As[(emt * 16 + r16) * 72 + kk * 32 + quad * 8]);
                short8 bf0 = *(const short8*)(&Bs[((entb + 0) * 16 + r16) * 72 + kk * 32 + quad * 8]);
                short8 bf1 = *(const short8*)(&Bs[((entb + 1) * 16 + r16) * 72 + kk * 32 + quad * 8]);
                ze0 = __builtin_amdgcn_mfma_f32_16x16x32_bf16(af, bf0, ze0, 0, 0, 0);
                ze1 = __builtin_amdgcn_mfma_f32_16x16x32_bf16(af, bf1, ze1, 0, 0, 0);
            }
            __syncthreads();
        }
        {
            int n0 = (entb + 0) * 16 + r16, n1 = (entb + 1) * 16 + r16;
            float bi0 = ld1<BF16>(benc, n0), bi1 = ld1<BF16>(benc, n1);
            #pragma unroll
            for (int reg = 0; reg < 4; ++reg) {
                int t = emt * 16 + quad * 4 + reg;
                zc[t * 72 + n0] = f2bf(ze0[reg] + bi0);
                zc[t * 72 + n1] = f2bf(ze1[reg] + bi1);
            }
        }
        __syncthreads();

        // ===== 2) xz = z @ W_in^T (MFMA), split x / gate =====
        floatx4 xza[2][4];
        #pragma unroll
        for (int mt = 0; mt < 2; ++mt)
            #pragma unroll
            for (int nt = 0; nt < 4; ++nt) xza[mt][nt] = (floatx4){0,0,0,0};
        #pragma unroll
        for (int kt = 0; kt < 2; ++kt) {
            short8 a0 = *(const short8*)(&zc[(0 * 16 + r16) * 72 + kt * 32 + quad * 8]);
            short8 a1 = *(const short8*)(&zc[(1 * 16 + r16) * 72 + kt * 32 + quad * 8]);
            #pragma unroll
            for (int nt = 0; nt < 4; ++nt) {
                xza[0][nt] = __builtin_amdgcn_mfma_f32_16x16x32_bf16(a0, win[nt][kt], xza[0][nt], 0, 0, 0);
                xza[1][nt] = __builtin_amdgcn_mfma_f32_16x16x32_bf16(a1, win[nt][kt], xza[1][nt], 0, 0, 0);
            }
        }
        #pragma unroll
        for (int mt = 0; mt < 2; ++mt)
            #pragma unroll
            for (int nt = 0; nt < 4; ++nt) {
                int n = wave * 64 + nt * 16 + r16;
                #pragma unroll
                for (int reg = 0; reg < 4; ++reg) {
                    int t = mt * 16 + quad * 4 + reg;
                    u16 v = f2bf(xza[mt][nt][reg]);
                    if (n < DI) xl[(t + 3) * 128 + n] = v;
                    else        gl[t * 128 + (n - DI)] = v;
                }
            }
        __syncthreads();

        // ===== 3) causal conv + SiLU -> xcb =====
        for (int it2 = tid; it2 < TCH * DI; it2 += 256) {
            int t = it2 >> 7, d = it2 & 127;
            float a = cb;
            #pragma unroll
            for (int k = 0; k < 4; ++k) a += bf2f(xl[(t + k) * 128 + d]) * cw[k];
            float s = a / (1.f + expf(-a));
            xcb[t * 136 + d] = f2bf(s);
        }
        __syncthreads();

        // ===== 4) x_dbl = xconv @ W_x^T (MFMA, waves 0..2) =====
        {
            floatx4 xda0 = (floatx4){0,0,0,0}, xda1 = (floatx4){0,0,0,0};
            if (wave < 3) {
                #pragma unroll
                for (int kt = 0; kt < 4; ++kt) {
                    short8 a0 = *(const short8*)(&xcb[(0 * 16 + r16) * 136 + kt * 32 + quad * 8]);
                    short8 a1 = *(const short8*)(&xcb[(1 * 16 + r16) * 136 + kt * 32 + quad * 8]);
                    xda0 = __builtin_amdgcn_mfma_f32_16x16x32_bf16(a0, wx[kt], xda0, 0, 0, 0);
                    xda1 = __builtin_amdgcn_mfma_f32_16x16x32_bf16(a1, wx[kt], xda1, 0, 0, 0);
                }
                int j = wave * 16 + r16;
                if (j < DTR + 2 * NST) {
                    #pragma unroll
                    for (int reg = 0; reg < 4; ++reg) {
                        xd2[(0 * 16 + quad * 4 + reg) * 40 + j] = xda0[reg];
                        xd2[(1 * 16 + quad * 4 + reg) * 40 + j] = xda1[reg];
                    }
                }
            }
        }
        __syncthreads();

        // ===== 5) dt = softplus(x_dbl[:, :4] @ W_dt^T + b_dt) =====
        for (int it2 = tid; it2 < TCH * DI; it2 += 256) {
            int t = it2 >> 7, d = it2 & 127;
            float v = bdt;
            #pragma unroll
            for (int r = 0; r < 4; ++r) v += xd2[t * 40 + r] * wdt[r];
            float sp = (v > 20.f) ? v : log1pf(expf(v));
            dtl[d * 33 + t] = f2bf(sp);
        }
        __syncthreads();

        // ===== 6) selective scan (threads 0..127); halo copy (128..255) =====
        if (tid < DI) {
            int d = tid;
            for (int t = 0; t < TCH; ++t) {
                float dtv = bf2f(dtl[d * 33 + t]);
                float xcv = bf2f(xcb[t * 136 + d]);
                float g   = bf2f(gl[t * 128 + d]);
                float dx  = dtv * xcv;
                const floatx4* Bp = (const floatx4*)(&xd2[t * 40 + DTR]);
                const floatx4* Cp = (const floatx4*)(&xd2[t * 40 + DTR + NST]);
                float y = 0.f;
                #pragma unroll
                for (int q = 0; q < 4; ++q) {
                    floatx4 Bv = Bp[q], Cv = Cp[q];
                    #pragma unroll
                    for (int e = 0; e < 4; ++e) {
                        int n = q * 4 + e;
                        float dA = expf(dtv * Areg[n]);
                        hreg[n] = dA * hreg[n] + dx * Bv[e];
                        y += hreg[n] * Cv[e];
                    }
                }
                y += Dv * xcv;
                y *= g / (1.f + expf(-g));
                accy += y;
            }
        } else {
            for (int it2 = tid - 128; it2 < 3 * 128; it2 += 128)
                xl[it2] = xl[32 * 128 + it2];
        }
        __syncthreads();
    }

    // ===== heads =====
    if (tid < DI) yb[tid] = accy * (1.f / (float)TT);
    __syncthreads();
    if (tid < DM) {
        float s = 0.f;
        #pragma unroll 8
        for (int k = 0; k < DI; ++k) s += yb[k] * ld1<BF16>(W_out, (size_t)tid * DI + k);
        es[tid] = s;
    }
    __syncthreads();
    if (tid < 128) {
        float s = ld1<BF16>(b_fc, tid);
        #pragma unroll 8
        for (int k = 0; k < DM; ++k) s += es[k] * ld1<BF16>(W_fc, (size_t)tid * DM + k);
        float th = tanhf(s);
        float xv = th > 0.f ? th : expm1f(th);
        xs[tid] = xv;
        st1<BF16>(out, (size_t)b * 128 + tid, xv);
    }
    __syncthreads();
    for (int j = tid; j < 512; j += 256) {
        int o = j & 255;
        bool is_mu = (j < 256);
        const void* w = is_mu ? W_mu : W_sig;
        float s = ld1<BF16>(is_mu ? b_mu : b_sig, o);
        #pragma unroll 8
        for (int k = 0; k < 128; ++k) s += xs[k] * ld1<BF16>(w, (size_t)o * 128 + k);
        if (is_mu) {
            st1<BF16>(out, 8192 + (size_t)b * 256 + o, s);
        } else {
            float e = s > 0.f ? s : expm1f(s);
            st1<BF16>(out, 8192 + 16384 + (size_t)b * 256 + o, e + 1.f + 1e-14f);
        }
    }
}

__global__ __launch_bounds__(256) void fused_mamba(
        const void* inp,   const void* Wenc, const void* benc, const void* W_in,
        const void* conv_w,const void* conv_b,const void* W_x, const void* W_dt,
        const void* b_dt,  const void* A_log,const void* D_skip,const void* W_out,
        const void* W_fc,  const void* b_fc, const void* W_mu, const void* b_mu,
        const void* W_sig, const void* b_sig, void* out) {
    // shared memory (single copy, shared by both template paths): ~58 KB
    __shared__ __align__(16) u16  As[32 * 72];
    __shared__ __align__(16) u16  Bs[64 * 72];
    __shared__ __align__(16) u16  zc[32 * 72];
    __shared__ __align__(16) u16  xl[35 * 128];
    __shared__ __align__(16) u16  gl[32 * 128];
    __shared__ __align__(16) u16  xcb[32 * 136];
    __shared__ __align__(16) float xd2[32 * 40];
    __shared__ __align__(16) u16  dtl[128 * 33];
    __shared__ float yb[128];
    __shared__ float es[64];
    __shared__ float xs[128];

    // dtype detect: A_log[0..1] = {log1, log2}. fp32 word0 = 0x00000000;
    // bf16 word0 = 0x3F310000 (elements 0,1 packed). Uniform branch.
    bool isbf = (((const u32*)A_log)[0] != 0u);
    if (isbf)
        body<true >(inp,Wenc,benc,W_in,conv_w,conv_b,W_x,W_dt,b_dt,A_log,D_skip,
                    W_out,W_fc,b_fc,W_mu,b_mu,W_sig,b_sig,out,
                    As,Bs,zc,xl,gl,xcb,xd2,dtl,yb,es,xs);
    else
        body<false>(inp,Wenc,benc,W_in,conv_w,conv_b,W_x,W_dt,b_dt,A_log,D_skip,
                    W_out,W_fc,b_fc,W_mu,b_mu,W_sig,b_sig,out,
                    As,Bs,zc,xl,gl,xcb,xd2,dtl,yb,es,xs);
}

extern "C" void kernel_launch(void* const* d_in, const int* in_sizes, int n_in,
                              void* d_out, int out_size, void* d_ws, size_t ws_size,
                              hipStream_t stream) {
    (void)in_sizes; (void)n_in; (void)d_ws; (void)ws_size; (void)out_size;
    fused_mamba<<<BB, 256, 0, stream>>>(d_in[0], d_in[1], d_in[2], d_in[3],
                                        d_in[4], d_in[5], d_in[6], d_in[7],
                                        d_in[8], d_in[9], d_in[10], d_in[11],
                                        d_in[12], d_in[13], d_in[14], d_in[15],
                                        d_in[16], d_in[17], d_out);
}